// Round 5
// baseline (925.837 us; speedup 1.0000x reference)
//
#include <hip/hip_runtime.h>
#include <math.h>

// SemiCurrSinkhornKnopp_stable on MI355X: persistent cooperative-style kernel.
// B=4, n=2048, k=512 (+1 slack). K = exp(-C/eps) = softmax(logits)^10 in LDS.
// R5: ONE grid barrier per iteration. Column sums go straight to a tiny
// colsum[3][4*513] LLC array via relaxed agent atomicAdd; after the barrier
// EVERY WG redundantly computes bn/err/stab for ALL batches from identical
// LLC data (uniform control flow, no owners, no bn broadcast, no 2nd barrier).
// Column state (vv,ww,bnL) replicated per-WG for all 4 batches in LDS.
// colsum triple-buffered (zeroed one iteration ahead); amaxa double-buffered.

#define NWG   512
#define NTHR  256
#define NROW  2048
#define KC    512
#define KP1   513
#define RPW   16
#define TOTC  2052         // 4*KP1
#define EPSI  0.1f
#define IEPS  10.0f
#define FI    0.90909090909090906f     // gamma/(gamma+eps)
#define FIM1  (-0.09090909090909094f)  // fi - 1.0
#define TINY  1.1920928955078125e-07f  // finfo(f32).eps
#define PA    (1.0f/2048.0f)
#define PBR   (0.5f/512.0f)
#define PBS   0.5f
#define STABT 1.0e8f
#define STOPE 1.0e-6f
#define ITMAX 50

#define AST(p, v)  __hip_atomic_store((p), (v), __ATOMIC_RELAXED, __HIP_MEMORY_SCOPE_AGENT)
#define ALD(p)     __hip_atomic_load((p), __ATOMIC_RELAXED, __HIP_MEMORY_SCOPE_AGENT)
#define AADD(p, v) __hip_atomic_fetch_add((p), (v), __ATOMIC_RELAXED, __HIP_MEMORY_SCOPE_AGENT)

// ws layout
#define OFF_LEAF   0        // 32 lines x 64B
#define OFF_ROOT   2048
#define OFF_GGEN   2112     // 32 lines x 64B
#define OFF_COL    4160     // colsum[3][2052] f32 = 24624B
#define OFF_AMAX   28800    // amaxa[2][512] f32 = 4096B
#define WS_ZERO    28800    // bytes to memset each launch

__device__ __forceinline__ float wsum(float v) {
#pragma unroll
  for (int m = 32; m > 0; m >>= 1) v += __shfl_xor(v, m, 64);
  return v;
}
__device__ __forceinline__ float wmaxf(float v) {
#pragma unroll
  for (int m = 32; m > 0; m >>= 1) v = fmaxf(v, __shfl_xor(v, m, 64));
  return v;
}

// Two-level fence-free grid barrier (relaxed agent atomics only).
// Entry: every thread drains its own vmcnt, then __syncthreads -> all prior
// sc1 stores/atomics of the whole WG are at the coherent point before arrival.
__device__ __forceinline__ void gbar(unsigned* leaf, unsigned* root, unsigned* ggen,
                                     unsigned mygen) {
  asm volatile("s_waitcnt vmcnt(0)" ::: "memory");
  __syncthreads();
  if (threadIdx.x == 0) {
    unsigned* lc = leaf + ((blockIdx.x >> 4) << 4);   // 16 WGs per 64B line
    unsigned p1 = __hip_atomic_fetch_add(lc, 1u, __ATOMIC_RELAXED, __HIP_MEMORY_SCOPE_AGENT);
    if ((p1 & 15u) == 15u) {
      unsigned p2 = __hip_atomic_fetch_add(root, 1u, __ATOMIC_RELAXED, __HIP_MEMORY_SCOPE_AGENT);
      if ((p2 & 31u) == 31u) {
#pragma unroll
        for (int i = 0; i < 32; ++i) AST(ggen + i * 16, mygen);
      }
    }
    unsigned* mg = ggen + ((blockIdx.x >> 4) << 4);
    while (ALD(mg) < mygen) __builtin_amdgcn_s_sleep(2);
  }
  __syncthreads();
}

__global__ __launch_bounds__(NTHR, 2)
void sinkhorn_kernel(const float* __restrict__ logits, float* __restrict__ out,
                     unsigned char* __restrict__ ws) {
  const int tid  = threadIdx.x;
  const int wg   = blockIdx.x;
  const int lane = tid & 63;
  const int wid  = tid >> 6;
  const int bat  = wg >> 7;       // batch 0..3
  const int slab = wg & 127;      // row slab within batch

  unsigned* leaf   = (unsigned*)(ws + OFF_LEAF);
  unsigned* root   = (unsigned*)(ws + OFF_ROOT);
  unsigned* ggen   = (unsigned*)(ws + OFF_GGEN);
  float*    colsum = (float*)(ws + OFF_COL);    // [3][TOTC]
  float*    amaxa  = (float*)(ws + OFF_AMAX);   // [2][NWG]

  __shared__ float Klds[RPW][KP1];              // 32.8 KB
  __shared__ float vv4[TOTC];                   // v for all 4 batches
  __shared__ float ww4[4 * KC];                 // w for all 4 batches
  __shared__ float bnL[TOTC];                   // last bn, all batches
  __shared__ float bb[KP1];                     // b, own batch only
  __shared__ float ev[KP1];
  __shared__ float u_s[RPW], kap[RPW], a_s[RPW], alp[RPW];
  __shared__ float wred[4], redS[4], redM[4], redA[4];

  // ---------------- init state ----------------
  for (int idx = tid; idx < TOTC; idx += NTHR) { vv4[idx] = 0.f; bnL[idx] = 1.f / 513.f; }
  for (int idx = tid; idx < 4 * KC; idx += NTHR) ww4[idx] = 1.f;
  for (int j = tid; j < KP1; j += NTHR) bb[j] = 1.f / 513.f;
  if (tid < RPW) { u_s[tid] = 0.f; kap[tid] = 1.f; a_s[tid] = 0.f; alp[tid] = 0.f; }

  // ---------------- build K = softmax(logits)^10 in LDS ----------------
  const size_t rowg0 = (size_t)bat * NROW + (size_t)slab * RPW;
  for (int r = wid; r < RPW; r += 4) {
    const float* lp = logits + (rowg0 + (size_t)r) * KC;
    float x[8];
    float mx = -INFINITY;
#pragma unroll
    for (int m = 0; m < 8; ++m) { x[m] = lp[lane + (m << 6)]; mx = fmaxf(mx, x[m]); }
    mx = wmaxf(mx);
    float sm = 0.f;
#pragma unroll
    for (int m = 0; m < 8; ++m) sm += expf(x[m] - mx);
    sm = wsum(sm);
    float lse = mx + logf(sm);
#pragma unroll
    for (int m = 0; m < 8; ++m) Klds[r][lane + (m << 6)] = expf((x[m] - lse) * IEPS);
    if (lane == 0) Klds[r][KC] = 1.f;   // slack column: C=0 -> K=1
  }
  __syncthreads();

  // ---------------- iterations: ONE barrier each ----------------
  float err_state = 1.f;
  int   stabled = 0;
  unsigned bargen = 0;
  int p = 0, p2 = 0;

  for (int t = 0; t < ITMAX; ++t) {
    if (!(err_state > STOPE)) break;     // uniform: err_state identical in all WGs

    // ---- phase A: ev, row sums -> a, alpha, amax; column atomicAdds ----
    for (int j = tid; j < KP1; j += NTHR) ev[j] = expf(vv4[bat * KP1 + j] * IEPS) * bb[j];
    __syncthreads();

    float wamax = 0.f;
    for (int r = wid; r < RPW; r += 4) {
      float s = 0.f;
#pragma unroll
      for (int m = 0; m < 8; ++m) { int j = lane + (m << 6); s += Klds[r][j] * ev[j]; }
      if (lane == 0) s += Klds[r][KC] * ev[KC];
      s = wsum(s);
      if (lane == 0) {
        float av = PA / (kap[r] * s);
        a_s[r] = av; alp[r] = kap[r] * av;
        wamax = fmaxf(wamax, av);
      }
    }
    if (lane == 0) wred[wid] = wamax;
    __syncthreads();
    if (tid == 0)
      AST(&amaxa[p2 * NWG + wg], fmaxf(fmaxf(wred[0], wred[1]), fmaxf(wred[2], wred[3])));

    // zero NEXT colsum buffer (consumed after next barrier; triple-buffered so
    // no laggard WG can still be reading it)
    int pn = p + 1; if (pn == 3) pn = 0;
    if (tid < 4) AST(&colsum[pn * TOTC + wg * 4 + tid], 0.f);
    if (wg == 0 && tid >= 4 && tid < 8) AST(&colsum[pn * TOTC + 2048 + (tid - 4)], 0.f);

    for (int j = tid; j < KP1; j += NTHR) {
      float acc = 0.f;
#pragma unroll
      for (int r = 0; r < RPW; ++r) acc += Klds[r][j] * alp[r];
      (void)AADD(&colsum[p * TOTC + bat * KP1 + j], acc);
    }
    gbar(leaf, root, ggen, ++bargen);

    // ---- scalar phase: ALL local & redundant (identical in every WG) ----
    float esq = 0.f, bmax = 0.f, amax = 0.f;
    for (int i = tid; i < NWG; i += NTHR) amax = fmaxf(amax, ALD(&amaxa[p2 * NWG + i]));
    for (int idx = tid; idx < TOTC; idx += NTHR) {
      int bt = idx / KP1;
      int j  = idx - bt * KP1;
      float tot = ALD(&colsum[p * TOTC + idx]);
      float c = expf(vv4[idx] * IEPS) * tot;
      float bnr = ((j < KC) ? PBR : PBS) / c;
      float bnj = (j < KC) ? powf(fmaxf(bnr, TINY), FI) * ww4[bt * KC + j] : bnr;
      float d = bnj - bnL[idx];
      bnL[idx] = bnj;                  // sole owner of this entry this phase
      esq += d * d; bmax = fmaxf(bmax, bnj);
    }
    esq = wsum(esq); bmax = wmaxf(bmax); amax = wmaxf(amax);
    if (lane == 0) { redS[wid] = esq; redM[wid] = bmax; redA[wid] = amax; }
    __syncthreads();
    float esq_t = redS[0] + redS[1] + redS[2] + redS[3];
    float mx_t  = fmaxf(fmaxf(redM[0], redM[1]), fmaxf(redM[2], redM[3]));
    mx_t = fmaxf(mx_t, fmaxf(fmaxf(redA[0], redA[1]), fmaxf(redA[2], redA[3])));
    int stab = (mx_t > STABT) ? 1 : 0;

    for (int idx = tid; idx < TOTC; idx += NTHR) {
      int bt = idx / KP1;
      int j  = idx - bt * KP1;
      float bnj = bnL[idx];
      if (stab) {
        vv4[idx] += EPSI * logf(bnj + TINY);
        if (j < KC) ww4[bt * KC + j] *= powf(fmaxf(bnj, TINY), FIM1);
        if (bt == bat) bb[j] = 1.f;
      } else if (bt == bat) {
        bb[j] = bnj;
      }
    }
    if (stab && tid < RPW) {
      u_s[tid] += EPSI * logf(a_s[tid]);
      kap[tid] = expf(u_s[tid] * IEPS);
    }
    err_state = sqrtf(esq_t);
    stabled = stab;
    __syncthreads();
    p = pn; p2 ^= 1;
  }

  // ---------------- final: plan = (stabled ? Q : a*Q*b^T) * n, drop slack ----------------
  for (int j = tid; j < KP1; j += NTHR) ev[j] = expf(vv4[bat * KP1 + j] * IEPS);
  __syncthreads();
  for (int r = wid; r < RPW; r += 4) {
    float* op = out + (rowg0 + (size_t)r) * KC;
    float kr = kap[r], ar = a_s[r];
#pragma unroll
    for (int m = 0; m < 8; ++m) {
      int j = lane + (m << 6);
      float Q = kr * Klds[r][j] * ev[j];
      float val = stabled ? Q : (ar * Q * bb[j]);
      op[j] = val * 2048.0f;
    }
  }
}

extern "C" void kernel_launch(void* const* d_in, const int* in_sizes, int n_in,
                              void* d_out, int out_size, void* d_ws, size_t ws_size,
                              hipStream_t stream) {
  (void)in_sizes; (void)n_in; (void)out_size; (void)ws_size;
  const float* logits = (const float*)d_in[0];
  float* out = (float*)d_out;
  // barrier counters + ggen + all colsum parities must start at 0 each launch
  (void)hipMemsetAsync(d_ws, 0, WS_ZERO, stream);
  sinkhorn_kernel<<<dim3(NWG), dim3(NTHR), 0, stream>>>(
      logits, out, (unsigned char*)d_ws);
}

// Round 6
// 538.982 us; speedup vs baseline: 1.7178x; 1.7178x over previous
//
#include <hip/hip_runtime.h>
#include <math.h>

// SemiCurrSinkhornKnopp_stable on MI355X: persistent cooperative-style kernel.
// B=4, n=2048, k=512 (+1 slack). K = softmax(logits)^10 in LDS.
// R6: 256 WGs x 512 thr (32 rows/WG, 1 WG/CU), ONE fence-free grid barrier
// per iteration + closing barrier. Column sums via 4-replica relaxed agent
// atomicAdd (16 adds/line burst instead of 128). Scalar phase redundant in
// every WG from identical LLC data, with fast-math __expf/__logf/__powf.
// Scratch (colsum 3-parity x 4-rep + amax x2) carved from d_out tail,
// memset-async'd to zero each launch; final store overwrites it after the
// closing barrier.

#define NWG   256
#define NTHR  512
#define NW    8            // waves per WG
#define NROW  2048
#define KC    512
#define KP1   513
#define RPW   32           // rows per workgroup
#define REP   4            // colsum replicas per batch
#define TOTC  2052         // 4*KP1
#define EPSI  0.1f
#define IEPS  10.0f
#define FI    0.90909090909090906f     // gamma/(gamma+eps)
#define FIM1  (-0.09090909090909094f)  // fi - 1.0
#define TINY  1.1920928955078125e-07f  // finfo(f32).eps
#define PA    (1.0f/2048.0f)
#define PBR   (0.5f/512.0f)
#define PBS   0.5f
#define STABT 1.0e8f
#define STOPE 1.0e-6f
#define ITMAX 50

#define AST(p, v)  __hip_atomic_store((p), (v), __ATOMIC_RELAXED, __HIP_MEMORY_SCOPE_AGENT)
#define ALD(p)     __hip_atomic_load((p), __ATOMIC_RELAXED, __HIP_MEMORY_SCOPE_AGENT)
#define AADD(p, v) __hip_atomic_fetch_add((p), (v), __ATOMIC_RELAXED, __HIP_MEMORY_SCOPE_AGENT)

// scratch carved from d_out tail
#define TOT_OUT    4194304                  // 4*2048*512 floats
#define SCR_COL_F  (3 * REP * TOTC)         // 24624 floats
#define SCR_AMX_F  (2 * NWG)                // 512 floats
#define SCR_FLOATS (SCR_COL_F + SCR_AMX_F)  // 25136
#define SCR_OFF    (TOT_OUT - SCR_FLOATS)   // 4169168

__device__ __forceinline__ float wsum(float v) {
#pragma unroll
  for (int m = 32; m > 0; m >>= 1) v += __shfl_xor(v, m, 64);
  return v;
}
__device__ __forceinline__ float wmaxf(float v) {
#pragma unroll
  for (int m = 32; m > 0; m >>= 1) v = fmaxf(v, __shfl_xor(v, m, 64));
  return v;
}

// Two-level fence-free grid barrier over 256 WGs (16 leaves x 16, root of 16).
// Every thread drains its own vmcnt (all sc1 stores/atomics at LLC), then
// __syncthreads, then thread 0 arrives. Relaxed agent atomics only.
__device__ __forceinline__ void gbar(unsigned* leaf, unsigned* root, unsigned* ggen,
                                     unsigned mygen) {
  asm volatile("s_waitcnt vmcnt(0)" ::: "memory");
  __syncthreads();
  if (threadIdx.x == 0) {
    unsigned* lc = leaf + ((blockIdx.x >> 4) << 4);   // 16 WGs per 64B line
    unsigned p1 = __hip_atomic_fetch_add(lc, 1u, __ATOMIC_RELAXED, __HIP_MEMORY_SCOPE_AGENT);
    if ((p1 & 15u) == 15u) {
      unsigned p2 = __hip_atomic_fetch_add(root, 1u, __ATOMIC_RELAXED, __HIP_MEMORY_SCOPE_AGENT);
      if ((p2 & 15u) == 15u) {
#pragma unroll
        for (int i = 0; i < 16; ++i) AST(ggen + i * 16, mygen);
      }
    }
    unsigned* mg = ggen + ((blockIdx.x >> 4) << 4);
    while (ALD(mg) < mygen) __builtin_amdgcn_s_sleep(2);
  }
  __syncthreads();
}

__global__ __launch_bounds__(NTHR)
void sinkhorn_kernel(const float* __restrict__ logits, float* __restrict__ out,
                     unsigned char* __restrict__ ws, float* __restrict__ scr) {
  const int tid  = threadIdx.x;
  const int wg   = blockIdx.x;
  const int lane = tid & 63;
  const int wid  = tid >> 6;
  const int bat  = wg >> 6;       // batch 0..3
  const int slab = wg & 63;       // row slab within batch
  const int rep  = slab & (REP - 1);

  unsigned* leaf   = (unsigned*)(ws);          // 16 lines x 64B
  unsigned* root   = (unsigned*)(ws + 1024);
  unsigned* ggen   = (unsigned*)(ws + 1088);   // 16 lines x 64B
  float*    colsum = scr;                      // [3][REP][TOTC]
  float*    amaxa  = scr + SCR_COL_F;          // [2][NWG]

  __shared__ float Klds[RPW][KP1];             // 65.7 KB
  __shared__ float vv4[TOTC];                  // v, all 4 batches
  __shared__ float ww4[4 * KC];                // w, all 4 batches
  __shared__ float bnL[TOTC];                  // last bn, all batches
  __shared__ float bb[KP1];                    // b, own batch
  __shared__ float ev[KP1];
  __shared__ float u_s[RPW], kap[RPW], a_s[RPW], alp[RPW];
  __shared__ float wred[NW], redS[NW], redM[NW], redA[NW];

  // ---------------- init state ----------------
  for (int idx = tid; idx < TOTC; idx += NTHR) { vv4[idx] = 0.f; bnL[idx] = 1.f / 513.f; }
  for (int idx = tid; idx < 4 * KC; idx += NTHR) ww4[idx] = 1.f;
  for (int j = tid; j < KP1; j += NTHR) bb[j] = 1.f / 513.f;
  if (tid < RPW) { u_s[tid] = 0.f; kap[tid] = 1.f; a_s[tid] = 0.f; alp[tid] = 0.f; }

  // ---------------- build K = softmax(logits)^10 in LDS (precise libm) ----------------
  const size_t rowg0 = (size_t)bat * NROW + (size_t)slab * RPW;
  for (int r = wid; r < RPW; r += NW) {
    const float* lp = logits + (rowg0 + (size_t)r) * KC;
    float x[8];
    float mx = -INFINITY;
#pragma unroll
    for (int m = 0; m < 8; ++m) { x[m] = lp[lane + (m << 6)]; mx = fmaxf(mx, x[m]); }
    mx = wmaxf(mx);
    float sm = 0.f;
#pragma unroll
    for (int m = 0; m < 8; ++m) sm += expf(x[m] - mx);
    sm = wsum(sm);
    float lse = mx + logf(sm);
#pragma unroll
    for (int m = 0; m < 8; ++m) Klds[r][lane + (m << 6)] = expf((x[m] - lse) * IEPS);
    if (lane == 0) Klds[r][KC] = 1.f;   // slack column: C=0 -> K=1
  }
  __syncthreads();

  // ---------------- iterations: ONE barrier each ----------------
  float err_state = 1.f;
  int   stabled = 0;
  unsigned bargen = 0;
  int p = 0, p2 = 0;

  for (int t = 0; t < ITMAX; ++t) {
    if (!(err_state > STOPE)) break;     // uniform: bit-identical in all WGs

    // ---- phase A: ev, row sums -> a/alpha/amax; replica column atomicAdds ----
    for (int j = tid; j < KP1; j += NTHR) ev[j] = __expf(vv4[bat * KP1 + j] * IEPS) * bb[j];
    __syncthreads();

    float wamax = 0.f;
    for (int r = wid; r < RPW; r += NW) {
      float s = 0.f;
#pragma unroll
      for (int m = 0; m < 8; ++m) { int j = lane + (m << 6); s += Klds[r][j] * ev[j]; }
      if (lane == 0) s += Klds[r][KC] * ev[KC];
      s = wsum(s);
      if (lane == 0) {
        float av = PA / (kap[r] * s);
        a_s[r] = av; alp[r] = kap[r] * av;
        wamax = fmaxf(wamax, av);
      }
    }
    if (lane == 0) wred[wid] = wamax;
    __syncthreads();
    if (tid == 0) {
      float m0 = wred[0];
#pragma unroll
      for (int i = 1; i < NW; ++i) m0 = fmaxf(m0, wred[i]);
      AST(&amaxa[p2 * NWG + wg], m0);
    }

    // zero NEXT colsum parity (triple-buffered; consumed after next barrier)
    int pn = p + 1; if (pn == 3) pn = 0;
    {
      int base = wg * 32;
      if (tid < 32) AST(&colsum[pn * (REP * TOTC) + base + tid], 0.f);
      if (wg == 0 && tid >= 32 && tid < 48)
        AST(&colsum[pn * (REP * TOTC) + 8192 + (tid - 32)], 0.f);
    }

    // column partials -> replica atomicAdd
    for (int j = tid; j < KP1; j += NTHR) {
      float acc = 0.f;
#pragma unroll
      for (int r = 0; r < RPW; ++r) acc += Klds[r][j] * alp[r];
      (void)AADD(&colsum[(p * REP + rep) * TOTC + bat * KP1 + j], acc);
    }
    gbar(leaf, root, ggen, ++bargen);

    // ---- scalar phase: redundant in every WG from identical LLC data ----
    float esq = 0.f, bmax = 0.f, amax = 0.f;
    for (int i = tid; i < NWG; i += NTHR) amax = fmaxf(amax, ALD(&amaxa[p2 * NWG + i]));
    for (int idx = tid; idx < TOTC; idx += NTHR) {
      int bt = idx / KP1;
      int j  = idx - bt * KP1;
      const float* cb = &colsum[p * (REP * TOTC) + idx];
      float tot = ALD(cb) + ALD(cb + TOTC) + ALD(cb + 2 * TOTC) + ALD(cb + 3 * TOTC);
      float c = __expf(vv4[idx] * IEPS) * tot;
      float bnr = ((j < KC) ? PBR : PBS) / c;
      float bnj = (j < KC) ? __powf(fmaxf(bnr, TINY), FI) * ww4[bt * KC + j] : bnr;
      float d = bnj - bnL[idx];
      bnL[idx] = bnj;
      esq += d * d; bmax = fmaxf(bmax, bnj);
    }
    esq = wsum(esq); bmax = wmaxf(bmax); amax = wmaxf(amax);
    if (lane == 0) { redS[wid] = esq; redM[wid] = bmax; redA[wid] = amax; }
    __syncthreads();
    float esq_t = 0.f, mx_t = 0.f;
#pragma unroll
    for (int i = 0; i < NW; ++i) {
      esq_t += redS[i];
      mx_t = fmaxf(mx_t, fmaxf(redM[i], redA[i]));
    }
    int stab = (mx_t > STABT) ? 1 : 0;

    for (int idx = tid; idx < TOTC; idx += NTHR) {
      int bt = idx / KP1;
      int j  = idx - bt * KP1;
      float bnj = bnL[idx];
      if (stab) {
        vv4[idx] += EPSI * __logf(bnj + TINY);
        if (j < KC) ww4[bt * KC + j] *= __powf(fmaxf(bnj, TINY), FIM1);
        if (bt == bat) bb[j] = 1.f;
      } else if (bt == bat) {
        bb[j] = bnj;
      }
    }
    if (stab && tid < RPW) {
      u_s[tid] += EPSI * __logf(a_s[tid]);
      kap[tid] = __expf(u_s[tid] * IEPS);
    }
    err_state = sqrtf(esq_t);
    stabled = stab;
    __syncthreads();
    p = pn; p2 ^= 1;
  }

  // closing barrier: all scalar-phase reads of scr done before output store
  // (final store overwrites the scr region carved from d_out)
  gbar(leaf, root, ggen, ++bargen);

  // ---------------- final: plan = (stabled ? Q : a*Q*b^T) * n, drop slack ----------------
  for (int j = tid; j < KP1; j += NTHR) ev[j] = __expf(vv4[bat * KP1 + j] * IEPS);
  __syncthreads();
  for (int r = wid; r < RPW; r += NW) {
    float* op = out + (rowg0 + (size_t)r) * KC;
    float kr = kap[r], ar = a_s[r];
#pragma unroll
    for (int m = 0; m < 8; ++m) {
      int j = lane + (m << 6);
      float Q = kr * Klds[r][j] * ev[j];
      float val = stabled ? Q : (ar * Q * bb[j]);
      op[j] = val * 2048.0f;
    }
  }
}

extern "C" void kernel_launch(void* const* d_in, const int* in_sizes, int n_in,
                              void* d_out, int out_size, void* d_ws, size_t ws_size,
                              hipStream_t stream) {
  (void)in_sizes; (void)n_in; (void)out_size; (void)ws_size;
  const float* logits = (const float*)d_in[0];
  float* out = (float*)d_out;
  float* scr = out + SCR_OFF;
  // barrier counters + ggen zeroed; colsum (all 3 parities) + amax zeroed
  (void)hipMemsetAsync(d_ws, 0, 2112, stream);
  (void)hipMemsetAsync(scr, 0, SCR_FLOATS * sizeof(float), stream);
  sinkhorn_kernel<<<dim3(NWG), dim3(NTHR), 0, stream>>>(
      logits, out, (unsigned char*)d_ws, scr);
}

// Round 7
// 444.332 us; speedup vs baseline: 2.0837x; 1.2130x over previous
//
#include <hip/hip_runtime.h>
#include <math.h>

// SemiCurrSinkhornKnopp_stable on MI355X: persistent kernel, NO global barrier.
// B=4, n=2048, k=512 (+1 slack). K = softmax(logits)^10 in LDS.
// R7: per-iteration sync = per-batch arrive counter (64 WGs) + 4 self-tagged
// {seq|f32} consensus slots (err^2, max) published by per-batch owner WGs.
// Each WG keeps ONLY its own batch's column state; bn computed 1 elem/thread.
// Column sums via 4-replica relaxed agent atomicAdd into LLC (d_out tail,
// triple-buffered). Sync scalars in d_ws. One done-counter sync before the
// epilogue store (which overwrites the scratch tail).

#define NWG   256
#define NTHR  512
#define NW    8            // waves per WG
#define NROW  2048
#define KC    512
#define KP1   513
#define RPW   32           // rows per workgroup
#define REP   4            // colsum replicas per batch
#define PARF  8208         // floats per parity = 4 batches * REP * KP1
#define EPSI  0.1f
#define IEPS  10.0f
#define FI    0.90909090909090906f     // gamma/(gamma+eps)
#define FIM1  (-0.09090909090909094f)  // fi - 1.0
#define TINY  1.1920928955078125e-07f  // finfo(f32).eps
#define PA    (1.0f/2048.0f)
#define PBR   (0.5f/512.0f)
#define PBS   0.5f
#define STABT 1.0e8f
#define STOPE 1.0e-6f
#define ITMAX 50

#define AST(p, v)  __hip_atomic_store((p), (v), __ATOMIC_RELAXED, __HIP_MEMORY_SCOPE_AGENT)
#define ALD(p)     __hip_atomic_load((p), __ATOMIC_RELAXED, __HIP_MEMORY_SCOPE_AGENT)
#define AADD(p, v) __hip_atomic_fetch_add((p), (v), __ATOMIC_RELAXED, __HIP_MEMORY_SCOPE_AGENT)

// d_ws layout (bytes): arrive 4x64B @0 | cons 32x64B @256 | amaxa[2][256] @2304
//                      | done @4352.  Zero 4416 bytes per launch.
#define WS_ZERO 4416

// colsum scratch carved from d_out tail: [3][4][REP][KP1] floats
#define TOT_OUT    4194304
#define SCR_FLOATS (3 * PARF)            // 24624
#define SCR_OFF    (TOT_OUT - SCR_FLOATS)

__device__ __forceinline__ float wsum(float v) {
#pragma unroll
  for (int m = 32; m > 0; m >>= 1) v += __shfl_xor(v, m, 64);
  return v;
}
__device__ __forceinline__ float wmaxf(float v) {
#pragma unroll
  for (int m = 32; m > 0; m >>= 1) v = fmaxf(v, __shfl_xor(v, m, 64));
  return v;
}

__global__ __launch_bounds__(NTHR)
void sinkhorn_kernel(const float* __restrict__ logits, float* __restrict__ out,
                     unsigned char* __restrict__ ws, float* __restrict__ scr) {
  const int tid  = threadIdx.x;
  const int wg   = blockIdx.x;
  const int lane = tid & 63;
  const int wid  = tid >> 6;
  const int bat  = wg >> 6;       // batch 0..3
  const int slab = wg & 63;       // row slab within batch
  const int rep  = slab & (REP - 1);
  const int grp  = wg & 7;        // consensus replica group

  unsigned*           arrive = (unsigned*)(ws);            // [4] @ b*16 u32
  unsigned long long* cons   = (unsigned long long*)(ws + 256); // 32 lines, [e,m] u64 pair each
  float*              amaxa  = (float*)(ws + 2304);        // [2][NWG]
  unsigned*           done   = (unsigned*)(ws + 4352);
  float*              colsum = scr;                        // [3][4][REP][KP1]

  __shared__ float Klds[RPW][KP1];              // 65.7 KB
  __shared__ float ev[KP1], vv[KP1], bb[KP1], bnL[KP1], ww[KC];
  __shared__ float u_s[RPW], kap[RPW], a_s[RPW], alp[RPW];
  __shared__ float wred[NW], redS[NW], redM[NW];
  __shared__ float c_es, c_mx;

  // ---------------- init own-batch state ----------------
  for (int j = tid; j < KP1; j += NTHR) { vv[j] = 0.f; bb[j] = 1.f / 513.f; bnL[j] = 1.f / 513.f; }
  for (int j = tid; j < KC; j += NTHR) ww[j] = 1.f;
  if (tid < RPW) { u_s[tid] = 0.f; kap[tid] = 1.f; a_s[tid] = 0.f; alp[tid] = 0.f; }

  // ---------------- build K = softmax(logits)^10 in LDS (precise libm) ----------------
  const size_t rowg0 = (size_t)bat * NROW + (size_t)slab * RPW;
  for (int r = wid; r < RPW; r += NW) {
    const float* lp = logits + (rowg0 + (size_t)r) * KC;
    float x[8];
    float mx = -INFINITY;
#pragma unroll
    for (int m = 0; m < 8; ++m) { x[m] = lp[lane + (m << 6)]; mx = fmaxf(mx, x[m]); }
    mx = wmaxf(mx);
    float sm = 0.f;
#pragma unroll
    for (int m = 0; m < 8; ++m) sm += expf(x[m] - mx);
    sm = wsum(sm);
    float lse = mx + logf(sm);
#pragma unroll
    for (int m = 0; m < 8; ++m) Klds[r][lane + (m << 6)] = expf((x[m] - lse) * IEPS);
    if (lane == 0) Klds[r][KC] = 1.f;   // slack column: C=0 -> K=1
  }
  __syncthreads();

  // ---------------- iterations ----------------
  float err_state = 1.f;
  int   stabled = 0;
  int   p = 0;

  for (int t = 0; t < ITMAX; ++t) {
    if (!(err_state > STOPE)) break;     // uniform: consensus value identical everywhere
    const int p2 = t & 1;

    // ---- phase A: ev, row sums -> a/alpha/amax; replica column atomicAdds ----
    for (int j = tid; j < KP1; j += NTHR) ev[j] = __expf(vv[j] * IEPS) * bb[j];
    __syncthreads();

    float wamax = 0.f;
    for (int r = wid; r < RPW; r += NW) {
      float s = 0.f;
#pragma unroll
      for (int m = 0; m < 8; ++m) { int j = lane + (m << 6); s += Klds[r][j] * ev[j]; }
      if (lane == 0) s += Klds[r][KC] * ev[KC];
      s = wsum(s);
      if (lane == 0) {
        float av = PA / (kap[r] * s);
        a_s[r] = av; alp[r] = kap[r] * av;
        wamax = fmaxf(wamax, av);
      }
    }
    if (lane == 0) wred[wid] = wamax;
    __syncthreads();
    if (tid == 0) {
      float m0 = wred[0];
#pragma unroll
      for (int i = 1; i < NW; ++i) m0 = fmaxf(m0, wred[i]);
      AST(&amaxa[p2 * NWG + wg], m0);
    }

    // zero NEXT colsum parity (triple-buffered; safe vs laggards, see R5/R6 notes)
    const int pn = (p == 2) ? 0 : (p + 1);
    if (tid < 32) AST(&colsum[pn * PARF + wg * 32 + tid], 0.f);
    if (wg == 0 && tid >= 32 && tid < 48) AST(&colsum[pn * PARF + 8192 + (tid - 32)], 0.f);

    // column partials -> replica atomicAdd (16 WGs per (batch,rep) address set)
    for (int j = tid; j < KP1; j += NTHR) {
      float acc = 0.f;
#pragma unroll
      for (int r = 0; r < RPW; ++r) acc += Klds[r][j] * alp[r];
      (void)AADD(&colsum[p * PARF + (bat * REP + rep) * KP1 + j], acc);
    }

    // ---- per-batch arrive sync (monotonic counter) ----
    asm volatile("s_waitcnt vmcnt(0)" ::: "memory");
    __syncthreads();
    if (tid == 0) {
      (void)AADD(&arrive[bat * 16], 1u);
      while (ALD(&arrive[bat * 16]) < 64u * (unsigned)(t + 1)) __builtin_amdgcn_s_sleep(2);
    }
    __syncthreads();

    // ---- bn for own batch: 1 column/thread (+ slack on thread 0) ----
    const float* cb0 = &colsum[p * PARF + bat * REP * KP1];
    float bn0, bn1 = 0.f, esq_c, mx_c;
    {
      const int j = tid;
      float tot = ALD(&cb0[j]) + ALD(&cb0[KP1 + j]) + ALD(&cb0[2 * KP1 + j]) + ALD(&cb0[3 * KP1 + j]);
      float c = __expf(vv[j] * IEPS) * tot;
      float bnr = ((j < KC) ? PBR : PBS) / c;
      bn0 = (j < KC) ? __powf(fmaxf(bnr, TINY), FI) * ww[j] : bnr;
      float d = bn0 - bnL[j];
      esq_c = d * d; mx_c = bn0;
    }
    if (tid == 0) {
      const int j = KC;  // slack column 512
      float tot = ALD(&cb0[j]) + ALD(&cb0[KP1 + j]) + ALD(&cb0[2 * KP1 + j]) + ALD(&cb0[3 * KP1 + j]);
      float c = __expf(vv[j] * IEPS) * tot;
      bn1 = PBS / c;
      float d = bn1 - bnL[j];
      esq_c += d * d; mx_c = fmaxf(mx_c, bn1);
    }

    // ---- owner WG (slab 0): reduce + publish self-tagged consensus ----
    if (slab == 0) {
      float am = (tid < 64) ? ALD(&amaxa[p2 * NWG + bat * 64 + tid]) : 0.f;
      mx_c = fmaxf(mx_c, am);
      float es = wsum(esq_c);
      float mx = wmaxf(mx_c);
      if (lane == 0) { redS[wid] = es; redM[wid] = mx; }
      __syncthreads();
      if (tid == 0) {
        float est = 0.f, mxt = 0.f;
#pragma unroll
        for (int i = 0; i < NW; ++i) { est += redS[i]; mxt = fmaxf(mxt, redM[i]); }
        unsigned long long seq = (unsigned long long)(unsigned)(t + 1) << 32;
        unsigned long long e64 = seq | (unsigned long long)__float_as_uint(est);
        unsigned long long m64 = seq | (unsigned long long)__float_as_uint(mxt);
#pragma unroll
        for (int g = 0; g < 8; ++g) {
          AST(&cons[(size_t)(bat * 8 + g) * 8 + 0], e64);
          AST(&cons[(size_t)(bat * 8 + g) * 8 + 1], m64);
        }
      }
    }

    // ---- poll 4-batch consensus (self-tagging: no fence needed) ----
    if (tid == 0) {
      const unsigned seq = (unsigned)(t + 1);
      float est = 0.f, mxt = 0.f;
#pragma unroll
      for (int b = 0; b < 4; ++b) {
        unsigned long long e, m;
        for (;;) { e = ALD(&cons[(size_t)(b * 8 + grp) * 8 + 0]);
                   if ((unsigned)(e >> 32) == seq) break; __builtin_amdgcn_s_sleep(1); }
        for (;;) { m = ALD(&cons[(size_t)(b * 8 + grp) * 8 + 1]);
                   if ((unsigned)(m >> 32) == seq) break; __builtin_amdgcn_s_sleep(1); }
        est += __uint_as_float((unsigned)e);
        mxt = fmaxf(mxt, __uint_as_float((unsigned)m));
      }
      c_es = est; c_mx = mxt;
    }
    __syncthreads();
    const float esq_t = c_es;
    const int stab = (c_mx > STABT) ? 1 : 0;

    // ---- state update (own batch, bn in registers) ----
    {
      const int j = tid;
      if (stab) {
        vv[j] += EPSI * __logf(bn0 + TINY);
        if (j < KC) ww[j] *= __powf(fmaxf(bn0, TINY), FIM1);
        bb[j] = 1.f; bnL[j] = 1.f;      // last_b gets post-reset b_n (ones)
      } else { bb[j] = bn0; bnL[j] = bn0; }
    }
    if (tid == 0) {
      const int j = KC;
      if (stab) { vv[j] += EPSI * __logf(bn1 + TINY); bb[j] = 1.f; bnL[j] = 1.f; }
      else      { bb[j] = bn1; bnL[j] = bn1; }
    }
    if (stab && tid < RPW) {
      u_s[tid] += EPSI * __logf(a_s[tid]);
      kap[tid] = __expf(u_s[tid] * IEPS);
    }
    err_state = sqrtf(esq_t);
    stabled = stab;
    __syncthreads();
    p = pn;
  }

  // ---- done-sync: all scr reads complete before epilogue overwrites scr ----
  asm volatile("s_waitcnt vmcnt(0)" ::: "memory");
  __syncthreads();
  if (tid == 0) {
    (void)AADD(done, 1u);
    while (ALD(done) < (unsigned)NWG) __builtin_amdgcn_s_sleep(2);
  }
  __syncthreads();

  // ---------------- final: plan = (stabled ? Q : a*Q*b^T) * n, drop slack ----------------
  for (int j = tid; j < KP1; j += NTHR) ev[j] = __expf(vv[j] * IEPS);
  __syncthreads();
  for (int r = wid; r < RPW; r += NW) {
    float* op = out + (rowg0 + (size_t)r) * KC;
    float kr = kap[r], ar = a_s[r];
#pragma unroll
    for (int m = 0; m < 8; ++m) {
      int j = lane + (m << 6);
      float Q = kr * Klds[r][j] * ev[j];
      float val = stabled ? Q : (ar * Q * bb[j]);
      op[j] = val * 2048.0f;
    }
  }
}

extern "C" void kernel_launch(void* const* d_in, const int* in_sizes, int n_in,
                              void* d_out, int out_size, void* d_ws, size_t ws_size,
                              hipStream_t stream) {
  (void)in_sizes; (void)n_in; (void)out_size; (void)ws_size;
  const float* logits = (const float*)d_in[0];
  float* out = (float*)d_out;
  float* scr = out + SCR_OFF;
  (void)hipMemsetAsync(d_ws, 0, WS_ZERO, stream);
  (void)hipMemsetAsync(scr, 0, SCR_FLOATS * sizeof(float), stream);
  sinkhorn_kernel<<<dim3(NWG), dim3(NTHR), 0, stream>>>(
      logits, out, (unsigned char*)d_ws, scr);
}